// Round 4
// baseline (96.761 us; speedup 1.0000x reference)
//
#include <hip/hip_runtime.h>
#include <math.h>

#define B   8
#define S   256
#define NT  50
#define E   64
#define NTE (NT * E)
#define EPSF 1e-16f
#define LOG2E 1.4426950408889634f

#define NW        4                 // waves per block
#define NTHREADS  (64 * NW)
#define LL_BLOCKS (B * S / 2)       // 1024 blocks; each handles rows (ih, S-1-ih)
#define IN_BLOCKS (B * NT)          // 400 blocks
#define TAB_ELEMS (NT * NTE)        // 160000 float2 = 1.25 MB

__device__ __forceinline__ float softplus(float x) {
    if (x > 20.0f) return x;
    return log1pf(__expf(x));
}

__device__ __forceinline__ float wave_reduce_sum(float v) {
    #pragma unroll
    for (int off = 32; off > 0; off >>= 1)
        v += __shfl_down(v, off, 64);
    return v;  // lane 0 holds the sum
}

// broadcast lane `l` (uniform) of v across the wave via register readlane
__device__ __forceinline__ float bcast_f(float v, int l) {
    return __int_as_float(__builtin_amdgcn_readlane(__float_as_int(v), l));
}
__device__ __forceinline__ int bcast_i(int v, int l) {
    return __builtin_amdgcn_readlane(v, l);
}

// ---------------------------------------------------------------------------
// Prekernel: fused table tab[tyj*NTE + tyi*E + e] = (A*ej, P*ej),
// ej = emb[tyj*E + e]. 1.25 MB, L2-resident.
// ---------------------------------------------------------------------------
__global__ __launch_bounds__(256) void pre_kernel(
    const float* __restrict__ emb,
    const float* __restrict__ Amat, const float* __restrict__ Pmat,
    float2* __restrict__ tab)
{
    const int i   = blockIdx.x * 256 + threadIdx.x;   // < TAB_ELEMS
    const int tyj = i / NTE;
    const float ej = emb[tyj * E + (i & 63)];
    tab[i] = make_float2(Amat[i] * ej, Pmat[i] * ej);
}

// ---------------------------------------------------------------------------
// Main kernel. Grid = LL_BLOCKS + IN_BLOCKS, 256 threads (4 waves).
//
// Event stream lives in REGISTERS: wave w's lane l holds event j = w + 4l
// (time + ty*NTE). Inner loop fetches iteration s's event via readlane
// (1-cycle register broadcast -> SGPR), so the coalesced tab load's address
// depends only on registers: no LDS latency in the chain, loads pipeline
// arbitrarily deep. Per (i,j,e): 2 readlane + 1 global_load_dwordx2 +
// sub/mul/mul/exp2/fma.
// ---------------------------------------------------------------------------
__global__ __launch_bounds__(NTHREADS) void main_kernel(
    const float* __restrict__ times, const int* __restrict__ types,
    const int* __restrict__ Tp,
    const float* __restrict__ emb,  const float* __restrict__ a,
    const float2* __restrict__ tab,
    float* __restrict__ ws_ll, float* __restrict__ ws_int)
{
    const int tid = threadIdx.x;
    const int e   = tid & 63;
    const int w   = tid >> 6;
    const int bid = blockIdx.x;
    const bool is_ll = (bid < LL_BLOCKS);
    const int b = is_ll ? (bid / (S / 2)) : ((bid - LL_BLOCKS) / NT);

    __shared__ float s_part[2][NW][E];
    __shared__ float s_row[2];

    // per-wave event registers: lane e holds event j = w + 4e
    const int   jmine  = w + 4 * e;
    const float t_ev   = times[b * S + jmine];
    const int   off_ev = types[b * S + jmine] * NTE;   // tyj * NTE

    if (is_ll) {
        const int ih = bid % (S / 2);
        const int rows[2] = { ih, S - 1 - ih };
        #pragma unroll
        for (int r = 0; r < 2; ++r) {
            const int   i      = rows[r];
            const float t_i    = times[b * S + i];          // uniform s_load
            const int   col    = types[b * S + i] * E + e;  // tyi*E + e
            const float negEi2 = -emb[col] * LOG2E;

            const int scnt = (i > w) ? ((i - w + 3) >> 2) : 0;
            float macc = 0.0f;
            #pragma unroll 4
            for (int s = 0; s < scnt; ++s) {
                const float t_j = bcast_f(t_ev, s);
                const int   ofs = bcast_i(off_ev, s);
                const float2 ap = tab[ofs + col];           // coalesced dwordx2
                macc = fmaf(ap.x, exp2f(negEi2 * ap.y * (t_i - t_j)), macc);
            }
            s_part[r][w][e] = macc;
        }
        __syncthreads();
        if (w < 2) {
            const int   i     = rows[w];
            const float t_i   = times[b * S + i];
            const int   col   = types[b * S + i] * E + e;
            const float emb_i = emb[col];
            float mt = 0.0f;
            #pragma unroll
            for (int q = 0; q < NW; ++q) mt += s_part[w][q][e];
            const float sp    = softplus(fmaf(emb_i, mt, emb_i * a[col]));
            const float inten = wave_reduce_sum(sp);
            if (e == 0)
                s_row[w] = (t_i >= 0.0f) ? logf(inten + EPSF) : 0.0f;
        }
        __syncthreads();
        if (tid == 0) ws_ll[bid] = s_row[0] + s_row[1];
    } else {
        const int   k      = (bid - LL_BLOCKS) % NT;
        const float Tf     = (float)(*Tp);
        const int   colk   = k * E + e;
        const float embk   = emb[colk];
        const float negEk2 = -embk * LOG2E;

        float acc = 0.0f;
        #pragma unroll 4
        for (int s = 0; s < S / NW; ++s) {                  // 64 iterations
            const float t_i = bcast_f(t_ev, s);
            const int   ofs = bcast_i(off_ev, s);
            const float2 ap = tab[ofs + colk];
            const float  c  = ap.x * exp2f(negEk2 * ap.y * (Tf - t_i));
            acc += (t_i >= 0.0f) ? c : 0.0f;                // predicated
        }
        s_part[0][w][e] = acc;
        __syncthreads();
        if (w == 0) {
            float mt = 0.0f;
            #pragma unroll
            for (int q = 0; q < NW; ++q) mt += s_part[0][q][e];
            const float sp = softplus(fmaf(embk, mt, embk * a[colk]));
            const float s  = wave_reduce_sum(sp);
            if (e == 0) ws_int[bid - LL_BLOCKS] = s;
        }
    }
}

// ---------------------------------------------------------------------------
// Finalize: one block, 4 waves.
// ---------------------------------------------------------------------------
__global__ __launch_bounds__(256) void finalize_kernel(
    const float* __restrict__ times,
    const int* __restrict__ Tp,
    const float* __restrict__ emb, const float* __restrict__ a,
    const float* __restrict__ ws_ll, const float* __restrict__ ws_int,
    float* __restrict__ out)
{
    const int t    = threadIdx.x;
    const int lane = t & 63;
    const int w    = t >> 6;
    const float Tf = (float)(*Tp);

    float llp = 0.0f;
    for (int idx = t; idx < LL_BLOCKS; idx += 256) llp += ws_ll[idx];
    float bs = 0.0f;
    for (int idx = t; idx < NTE; idx += 256) bs += softplus(emb[idx] * a[idx]);

    __shared__ float red[256], red2[256];
    red[t] = llp; red2[t] = bs;

    __shared__ float s_first[B], s_last[B], s_iT[B], s_any[B];
    for (int b = w; b < B; b += 4) {
        float mn = 1e30f, mx = -1e30f;
        #pragma unroll
        for (int q = 0; q < S / 64; ++q) {
            const float tv = times[b * S + q * 64 + lane];
            const bool valid = (tv >= 0.0f);
            mn = fminf(mn, valid ? tv : 1e30f);
            mx = fmaxf(mx, valid ? tv : -1e30f);
        }
        float iv = (lane < NT) ? ws_int[b * NT + lane] : 0.0f;
        #pragma unroll
        for (int off = 32; off > 0; off >>= 1) {
            mn = fminf(mn, __shfl_down(mn, off, 64));
            mx = fmaxf(mx, __shfl_down(mx, off, 64));
            iv += __shfl_down(iv, off, 64);
        }
        if (lane == 0) {
            const bool any_valid = (mn < 1e29f);
            s_any[b]   = any_valid ? 1.0f : 0.0f;
            s_first[b] = any_valid ? mn : 0.0f;
            s_last[b]  = any_valid ? mx : 0.0f;
            s_iT[b]    = iv;
        }
    }
    __syncthreads();

    for (int off = 128; off > 0; off >>= 1) {
        if (t < off) { red[t] += red[t + off]; red2[t] += red2[t + off]; }
        __syncthreads();
    }

    if (t == 0) {
        const float base_sum = red2[0];
        float integral = 0.0f;
        #pragma unroll
        for (int b = 0; b < B; ++b) {
            integral += (s_any[b] > 0.5f)
                ? s_iT[b] * (Tf - s_last[b]) + base_sum * s_first[b]
                : base_sum * Tf;
        }
        out[0] = integral - red[0];
    }
}

extern "C" void kernel_launch(void* const* d_in, const int* in_sizes, int n_in,
                              void* d_out, int out_size, void* d_ws, size_t ws_size,
                              hipStream_t stream) {
    const float* times = (const float*)d_in[0];
    const int*   types = (const int*)d_in[1];
    const int*   Tp    = (const int*)d_in[2];
    const float* emb   = (const float*)d_in[3];
    const float* a     = (const float*)d_in[4];
    const float* Amat  = (const float*)d_in[5];
    const float* Pmat  = (const float*)d_in[6];

    float*  ws     = (float*)d_ws;
    float*  ws_ll  = ws;                    // [0, 1024)
    float*  ws_int = ws + LL_BLOCKS;        // [1024, 1424)
    float2* tab    = (float2*)(ws + 2048);  // 8 KB offset, 1.25 MB table
    float*  out    = (float*)d_out;

    pre_kernel<<<TAB_ELEMS / 256, 256, 0, stream>>>(emb, Amat, Pmat, tab);
    main_kernel<<<LL_BLOCKS + IN_BLOCKS, NTHREADS, 0, stream>>>(
        times, types, Tp, emb, a, tab, ws_ll, ws_int);
    finalize_kernel<<<1, 256, 0, stream>>>(times, Tp, emb, a, ws_ll, ws_int, out);
}